// Round 1
// baseline (313.725 us; speedup 1.0000x reference)
//
#include <hip/hip_runtime.h>
#include <math.h>

#define KW_ELEMS 294912   // 3*3*128*256
#define LR_GD 0.01

// ws layout (bytes):
//   0   : double sum_w
//   8   : double sum_w2
//   16  : int    Gint[15]   (upper triangle of B B^T counts)
//   80  : double c5[5]      (B w sums)
//   128 : float  alphas[5]
//   160 : float  W_eff[294912]
#define WS_GINT_OFF  16
#define WS_C5_OFF    80
#define WS_ALPHA_OFF 128
#define WS_WEFF_OFF  160

// ---------------- K1: sum / sumsq of weights (f64) ----------------
__global__ void k_stats(const float* __restrict__ w, double* __restrict__ wsd) {
    __shared__ double s1[256];
    __shared__ double s2[256];
    int tid = threadIdx.x;
    double a = 0.0, b = 0.0;
    for (int i = blockIdx.x * blockDim.x + tid; i < KW_ELEMS; i += gridDim.x * blockDim.x) {
        double v = (double)w[i];
        a += v; b += v * v;
    }
    s1[tid] = a; s2[tid] = b;
    __syncthreads();
    for (int off = 128; off > 0; off >>= 1) {
        if (tid < off) { s1[tid] += s1[tid + off]; s2[tid] += s2[tid + off]; }
        __syncthreads();
    }
    if (tid == 0) { atomicAdd(&wsd[0], s1[0]); atomicAdd(&wsd[1], s2[0]); }
}

// ---------------- K2: G = B B^T counts (int, exact), c = B w (f64) ----------------
__global__ void k_gc(const float* __restrict__ w, void* __restrict__ wsv) {
    const double* wsd = (const double*)wsv;
    int*    gw = (int*)((char*)wsv + WS_GINT_OFF);
    double* cw = (double*)((char*)wsv + WS_C5_OFF);

    double mean = wsd[0] / (double)KW_ELEMS;
    double var  = wsd[1] / (double)KW_ELEMS - mean * mean;
    float meanf = (float)mean;
    float sigf  = sqrtf((float)var);
    float sh[5];
    #pragma unroll
    for (int m = 0; m < 5; m++) sh[m] = (-1.0f + 0.5f * (float)m) * sigf;

    int g[15];
    double c[5];
    #pragma unroll
    for (int t = 0; t < 15; t++) g[t] = 0;
    #pragma unroll
    for (int i = 0; i < 5; i++) c[i] = 0.0;

    for (int idx = blockIdx.x * blockDim.x + threadIdx.x; idx < KW_ELEMS;
         idx += gridDim.x * blockDim.x) {
        float wf = w[idx];
        float base = wf - meanf;
        int s[5];
        #pragma unroll
        for (int m = 0; m < 5; m++) {
            float arg = base + sh[m];
            s[m] = (arg > 0.0f) ? 1 : ((arg < 0.0f) ? -1 : 0);
        }
        int t = 0;
        #pragma unroll
        for (int i = 0; i < 5; i++) {
            #pragma unroll
            for (int j = i; j < 5; j++) { g[t] += s[i] * s[j]; t++; }
            c[i] += (double)s[i] * (double)wf;
        }
    }
    // wave reduction (64 lanes)
    #pragma unroll
    for (int t = 0; t < 15; t++) {
        int v = g[t];
        for (int off = 32; off > 0; off >>= 1) v += __shfl_down(v, off, 64);
        g[t] = v;
    }
    #pragma unroll
    for (int i = 0; i < 5; i++) {
        double v = c[i];
        for (int off = 32; off > 0; off >>= 1) v += __shfl_down(v, off, 64);
        c[i] = v;
    }
    if ((threadIdx.x & 63) == 0) {
        #pragma unroll
        for (int t = 0; t < 15; t++) atomicAdd(&gw[t], g[t]);
        #pragma unroll
        for (int i = 0; i < 5; i++) atomicAdd(&cw[i], c[i]);
    }
}

// ---------------- K3: closed-form 500-step GD ----------------
__device__ __forceinline__ void mm5(double* __restrict__ D,
                                    const double* __restrict__ X,
                                    const double* __restrict__ Y) {
    #pragma unroll
    for (int i = 0; i < 5; i++) {
        #pragma unroll
        for (int j = 0; j < 5; j++) {
            double s = 0.0;
            #pragma unroll
            for (int k = 0; k < 5; k++) s += X[i * 5 + k] * Y[k * 5 + j];
            D[i * 5 + j] = s;
        }
    }
}

__global__ void k_alpha(const float* __restrict__ a0f, void* __restrict__ wsv) {
    const int*    gw = (const int*)((const char*)wsv + WS_GINT_OFF);
    const double* cw = (const double*)((const char*)wsv + WS_C5_OFF);
    float* alph = (float*)((char*)wsv + WS_ALPHA_OFF);

    double G[25], C[5];
    {
        int t = 0;
        #pragma unroll
        for (int i = 0; i < 5; i++) {
            #pragma unroll
            for (int j = i; j < 5; j++) {
                double v = (double)gw[t] / (double)KW_ELEMS; t++;
                G[i * 5 + j] = v; G[j * 5 + i] = v;
            }
        }
    }
    #pragma unroll
    for (int i = 0; i < 5; i++) C[i] = cw[i] / (double)KW_ELEMS;

    // Cholesky G = L L^T  (G is SPD Gram matrix)
    double L[25];
    #pragma unroll
    for (int i = 0; i < 25; i++) L[i] = 0.0;
    #pragma unroll
    for (int i = 0; i < 5; i++) {
        #pragma unroll
        for (int j = 0; j <= i; j++) {
            double s = G[i * 5 + j];
            #pragma unroll
            for (int k = 0; k < j; k++) s -= L[i * 5 + k] * L[j * 5 + k];
            if (i == j) L[i * 5 + j] = sqrt(s);
            else        L[i * 5 + j] = s / L[j * 5 + j];
        }
    }
    // solve L y = C ; L^T astar = y
    double y[5], astar[5];
    #pragma unroll
    for (int i = 0; i < 5; i++) {
        double s = C[i];
        #pragma unroll
        for (int k = 0; k < i; k++) s -= L[i * 5 + k] * y[k];
        y[i] = s / L[i * 5 + i];
    }
    #pragma unroll
    for (int ii = 0; ii < 5; ii++) {
        int i = 4 - ii;
        double s = y[i];
        #pragma unroll
        for (int k = 0; k < 5; k++) if (k > i) s -= L[k * 5 + i] * astar[k];
        astar[i] = s / L[i * 5 + i];
    }
    // A = I - LR*G ;  R = A^500  (500 = 0b111110100)
    double A[25], R[25], T[25];
    #pragma unroll
    for (int i = 0; i < 25; i++) A[i] = ((i % 6) == 0 ? 1.0 : 0.0) - LR_GD * G[i];
    #pragma unroll
    for (int i = 0; i < 25; i++) R[i] = A[i];
    const int bits[8] = {1, 1, 1, 1, 0, 1, 0, 0};
    #pragma unroll
    for (int s = 0; s < 8; s++) {
        mm5(T, R, R);
        if (bits[s]) { mm5(R, T, A); }
        else {
            #pragma unroll
            for (int i = 0; i < 25; i++) R[i] = T[i];
        }
    }
    // a500 = R (a0 - astar) + astar
    double d0[5];
    #pragma unroll
    for (int i = 0; i < 5; i++) d0[i] = (double)a0f[i] - astar[i];
    if (threadIdx.x == 0) {
        #pragma unroll
        for (int i = 0; i < 5; i++) {
            double s = astar[i];
            #pragma unroll
            for (int j = 0; j < 5; j++) s += R[i * 5 + j] * d0[j];
            alph[i] = (float)s;
        }
    }
}

// ---------------- K4: W_eff = sum_m alpha_m * sign(w - mean + shift_m*sigma) ----------------
__global__ void k_weff(const float* __restrict__ w, void* __restrict__ wsv) {
    const double* wsd = (const double*)wsv;
    const float* alph = (const float*)((const char*)wsv + WS_ALPHA_OFF);
    float* weff = (float*)((char*)wsv + WS_WEFF_OFF);
    int idx = blockIdx.x * blockDim.x + threadIdx.x;
    if (idx >= KW_ELEMS) return;
    double mean = wsd[0] / (double)KW_ELEMS;
    double var  = wsd[1] / (double)KW_ELEMS - mean * mean;
    float meanf = (float)mean;
    float sigf  = sqrtf((float)var);
    float base = w[idx] - meanf;
    float acc = 0.0f;
    #pragma unroll
    for (int m = 0; m < 5; m++) {
        float arg = base + (-1.0f + 0.5f * (float)m) * sigf;
        float s = (arg > 0.0f) ? 1.0f : ((arg < 0.0f) ? -1.0f : 0.0f);
        acc += alph[m] * s;
    }
    weff[idx] = acc;
}

// ---------------- K6: fused binarize-x + 3x3 conv ----------------
// block = (b, h, cout-half); 256 threads: tid&127 -> cout offset, tid>>7 -> w-half
__global__ __launch_bounds__(256) void k_conv(
    const float* __restrict__ x, const float* __restrict__ shiftp,
    const float* __restrict__ beta, const void* __restrict__ wsv,
    float* __restrict__ out) {
    const float* weff = (const float*)((const char*)wsv + WS_WEFF_OFF);
    __shared__ float lds[3 * 34 * 128];   // rows h-1..h+1, positions -1..32, 128 cin

    int bid  = blockIdx.x;
    int half = bid & 1;
    int h    = (bid >> 1) & 31;
    int b    = bid >> 6;
    int tid  = threadIdx.x;

    float s0 = shiftp[0], s1 = shiftp[1], s2 = shiftp[2];
    float be0 = beta[0], be1 = beta[1], be2 = beta[2];

    // stage X_eff rows into LDS (zero padding at edges), computed on the fly
    for (int i = tid; i < 3 * 34 * 128; i += 256) {
        int cin = i & 127;
        int pos = (i >> 7) % 34;
        int dh  = (i >> 7) / 34;
        int r  = h - 1 + dh;
        int wp = pos - 1;
        float v = 0.0f;
        if (r >= 0 && r < 32 && wp >= 0 && wp < 32) {
            float xv = x[(((b * 32 + r) * 32) + wp) * 128 + cin];
            float t0 = fminf(fmaxf(xv + s0, 0.0f), 1.0f) - 0.5f;
            float t1 = fminf(fmaxf(xv + s1, 0.0f), 1.0f) - 0.5f;
            float t2 = fminf(fmaxf(xv + s2, 0.0f), 1.0f) - 0.5f;
            float g0 = (t0 > 0.0f) ? 1.0f : ((t0 < 0.0f) ? -1.0f : 0.0f);
            float g1 = (t1 > 0.0f) ? 1.0f : ((t1 < 0.0f) ? -1.0f : 0.0f);
            float g2 = (t2 > 0.0f) ? 1.0f : ((t2 < 0.0f) ? -1.0f : 0.0f);
            v = be0 * g0 + be1 * g1 + be2 * g2;
        }
        lds[i] = v;
    }
    __syncthreads();

    int c  = (half << 7) + (tid & 127);
    int wh = (tid >> 7) << 4;   // 0 or 16

    float acc[16];
    #pragma unroll
    for (int p = 0; p < 16; p++) acc[p] = 0.0f;

    #pragma unroll
    for (int dh = 0; dh < 3; dh++) {
        #pragma unroll
        for (int dw = 0; dw < 3; dw++) {
            const float* wptr = weff + (dh * 3 + dw) * (128 * 256) + c;
            const float* xrow = lds + (dh * 34 + wh + dw) * 128;
            #pragma unroll 4
            for (int c4 = 0; c4 < 32; c4++) {
                float w0 = wptr[(c4 * 4 + 0) * 256];
                float w1 = wptr[(c4 * 4 + 1) * 256];
                float w2 = wptr[(c4 * 4 + 2) * 256];
                float w3 = wptr[(c4 * 4 + 3) * 256];
                #pragma unroll
                for (int p = 0; p < 16; p++) {
                    float4 xv = *(const float4*)(&xrow[p * 128 + c4 * 4]);
                    acc[p] = fmaf(xv.x, w0, acc[p]);
                    acc[p] = fmaf(xv.y, w1, acc[p]);
                    acc[p] = fmaf(xv.z, w2, acc[p]);
                    acc[p] = fmaf(xv.w, w3, acc[p]);
                }
            }
        }
    }

    int obase = ((b * 32 + h) * 32 + wh) * 256 + c;
    #pragma unroll
    for (int p = 0; p < 16; p++) out[obase + p * 256] = acc[p];
}

extern "C" void kernel_launch(void* const* d_in, const int* in_sizes, int n_in,
                              void* d_out, int out_size, void* d_ws, size_t ws_size,
                              hipStream_t stream) {
    const float* x      = (const float*)d_in[0];
    const float* w      = (const float*)d_in[1];
    const float* shiftp = (const float*)d_in[2];
    const float* beta   = (const float*)d_in[3];
    const float* a0     = (const float*)d_in[4];
    float* out = (float*)d_out;

    hipMemsetAsync(d_ws, 0, 160, stream);
    k_stats<<<256, 256, 0, stream>>>(w, (double*)d_ws);
    k_gc<<<128, 256, 0, stream>>>(w, d_ws);
    k_alpha<<<1, 64, 0, stream>>>(a0, d_ws);
    k_weff<<<(KW_ELEMS + 255) / 256, 256, 0, stream>>>(w, d_ws);
    k_conv<<<512, 256, 0, stream>>>(x, shiftp, beta, d_ws, out);
}

// Round 2
// 122.998 us; speedup vs baseline: 2.5506x; 2.5506x over previous
//
#include <hip/hip_runtime.h>
#include <math.h>

#define KW_ELEMS 294912   // 3*3*128*256
#define LR_GD 0.01

// ws layout (bytes):
//   0   : double sum_w
//   8   : double sum_w2
//   16  : int    Gint[15]   (upper triangle of B B^T counts)
//   80  : double c5[5]      (B w sums)
//   128 : float  alphas[5]
//   160 : float  W_eff[294912]
#define WS_GINT_OFF  16
#define WS_C5_OFF    80
#define WS_ALPHA_OFF 128
#define WS_WEFF_OFF  160

// ---------------- K1: sum / sumsq of weights (f64) ----------------
__global__ void k_stats(const float* __restrict__ w, double* __restrict__ wsd) {
    __shared__ double s1[256];
    __shared__ double s2[256];
    int tid = threadIdx.x;
    double a = 0.0, b = 0.0;
    for (int i = blockIdx.x * blockDim.x + tid; i < KW_ELEMS; i += gridDim.x * blockDim.x) {
        double v = (double)w[i];
        a += v; b += v * v;
    }
    s1[tid] = a; s2[tid] = b;
    __syncthreads();
    for (int off = 128; off > 0; off >>= 1) {
        if (tid < off) { s1[tid] += s1[tid + off]; s2[tid] += s2[tid + off]; }
        __syncthreads();
    }
    if (tid == 0) { atomicAdd(&wsd[0], s1[0]); atomicAdd(&wsd[1], s2[0]); }
}

// ---------------- K2: G = B B^T counts (int, exact), c = B w (f64) ----------------
// One atomic set per BLOCK (wave reduce -> LDS -> leader atomics).
__global__ void k_gc(const float* __restrict__ w, void* __restrict__ wsv) {
    const double* wsd = (const double*)wsv;
    int*    gw = (int*)((char*)wsv + WS_GINT_OFF);
    double* cw = (double*)((char*)wsv + WS_C5_OFF);

    __shared__ int    lg[4][15];
    __shared__ double lc[4][5];

    double mean = wsd[0] / (double)KW_ELEMS;
    double var  = wsd[1] / (double)KW_ELEMS - mean * mean;
    float meanf = (float)mean;
    float sigf  = sqrtf((float)var);
    float sh[5];
    #pragma unroll
    for (int m = 0; m < 5; m++) sh[m] = (-1.0f + 0.5f * (float)m) * sigf;

    int g[15];
    double c[5];
    #pragma unroll
    for (int t = 0; t < 15; t++) g[t] = 0;
    #pragma unroll
    for (int i = 0; i < 5; i++) c[i] = 0.0;

    for (int idx = blockIdx.x * blockDim.x + threadIdx.x; idx < KW_ELEMS;
         idx += gridDim.x * blockDim.x) {
        float wf = w[idx];
        float base = wf - meanf;
        int s[5];
        #pragma unroll
        for (int m = 0; m < 5; m++) {
            float arg = base + sh[m];
            s[m] = (arg > 0.0f) ? 1 : ((arg < 0.0f) ? -1 : 0);
        }
        int t = 0;
        #pragma unroll
        for (int i = 0; i < 5; i++) {
            #pragma unroll
            for (int j = i; j < 5; j++) { g[t] += s[i] * s[j]; t++; }
            c[i] += (double)s[i] * (double)wf;
        }
    }
    // wave reduction (64 lanes)
    #pragma unroll
    for (int t = 0; t < 15; t++) {
        int v = g[t];
        for (int off = 32; off > 0; off >>= 1) v += __shfl_down(v, off, 64);
        g[t] = v;
    }
    #pragma unroll
    for (int i = 0; i < 5; i++) {
        double v = c[i];
        for (int off = 32; off > 0; off >>= 1) v += __shfl_down(v, off, 64);
        c[i] = v;
    }
    int wave = threadIdx.x >> 6;
    if ((threadIdx.x & 63) == 0) {
        #pragma unroll
        for (int t = 0; t < 15; t++) lg[wave][t] = g[t];
        #pragma unroll
        for (int i = 0; i < 5; i++) lc[wave][i] = c[i];
    }
    __syncthreads();
    if (threadIdx.x == 0) {
        #pragma unroll
        for (int t = 0; t < 15; t++) {
            int v = lg[0][t] + lg[1][t] + lg[2][t] + lg[3][t];
            atomicAdd(&gw[t], v);
        }
        #pragma unroll
        for (int i = 0; i < 5; i++) {
            double v = lc[0][i] + lc[1][i] + lc[2][i] + lc[3][i];
            atomicAdd(&cw[i], v);
        }
    }
}

// ---------------- K3: closed-form 500-step GD ----------------
__device__ __forceinline__ void mm5(double* __restrict__ D,
                                    const double* __restrict__ X,
                                    const double* __restrict__ Y) {
    #pragma unroll
    for (int i = 0; i < 5; i++) {
        #pragma unroll
        for (int j = 0; j < 5; j++) {
            double s = 0.0;
            #pragma unroll
            for (int k = 0; k < 5; k++) s += X[i * 5 + k] * Y[k * 5 + j];
            D[i * 5 + j] = s;
        }
    }
}

__global__ void k_alpha(const float* __restrict__ a0f, void* __restrict__ wsv) {
    const int*    gw = (const int*)((const char*)wsv + WS_GINT_OFF);
    const double* cw = (const double*)((const char*)wsv + WS_C5_OFF);
    float* alph = (float*)((char*)wsv + WS_ALPHA_OFF);

    double G[25], C[5];
    {
        int t = 0;
        #pragma unroll
        for (int i = 0; i < 5; i++) {
            #pragma unroll
            for (int j = i; j < 5; j++) {
                double v = (double)gw[t] / (double)KW_ELEMS; t++;
                G[i * 5 + j] = v; G[j * 5 + i] = v;
            }
        }
    }
    #pragma unroll
    for (int i = 0; i < 5; i++) C[i] = cw[i] / (double)KW_ELEMS;

    // Cholesky G = L L^T
    double L[25];
    #pragma unroll
    for (int i = 0; i < 25; i++) L[i] = 0.0;
    #pragma unroll
    for (int i = 0; i < 5; i++) {
        #pragma unroll
        for (int j = 0; j <= i; j++) {
            double s = G[i * 5 + j];
            #pragma unroll
            for (int k = 0; k < j; k++) s -= L[i * 5 + k] * L[j * 5 + k];
            if (i == j) L[i * 5 + j] = sqrt(s);
            else        L[i * 5 + j] = s / L[j * 5 + j];
        }
    }
    double y[5], astar[5];
    #pragma unroll
    for (int i = 0; i < 5; i++) {
        double s = C[i];
        #pragma unroll
        for (int k = 0; k < i; k++) s -= L[i * 5 + k] * y[k];
        y[i] = s / L[i * 5 + i];
    }
    #pragma unroll
    for (int ii = 0; ii < 5; ii++) {
        int i = 4 - ii;
        double s = y[i];
        #pragma unroll
        for (int k = 0; k < 5; k++) if (k > i) s -= L[k * 5 + i] * astar[k];
        astar[i] = s / L[i * 5 + i];
    }
    // A = I - LR*G ;  R = A^500
    double A[25], R[25], T[25];
    #pragma unroll
    for (int i = 0; i < 25; i++) A[i] = ((i % 6) == 0 ? 1.0 : 0.0) - LR_GD * G[i];
    #pragma unroll
    for (int i = 0; i < 25; i++) R[i] = A[i];
    const int bits[8] = {1, 1, 1, 1, 0, 1, 0, 0};
    #pragma unroll
    for (int s = 0; s < 8; s++) {
        mm5(T, R, R);
        if (bits[s]) { mm5(R, T, A); }
        else {
            #pragma unroll
            for (int i = 0; i < 25; i++) R[i] = T[i];
        }
    }
    double d0[5];
    #pragma unroll
    for (int i = 0; i < 5; i++) d0[i] = (double)a0f[i] - astar[i];
    if (threadIdx.x == 0) {
        #pragma unroll
        for (int i = 0; i < 5; i++) {
            double s = astar[i];
            #pragma unroll
            for (int j = 0; j < 5; j++) s += R[i * 5 + j] * d0[j];
            alph[i] = (float)s;
        }
    }
}

// ---------------- K4: W_eff ----------------
__global__ void k_weff(const float* __restrict__ w, void* __restrict__ wsv) {
    const double* wsd = (const double*)wsv;
    const float* alph = (const float*)((const char*)wsv + WS_ALPHA_OFF);
    float* weff = (float*)((char*)wsv + WS_WEFF_OFF);
    int idx = blockIdx.x * blockDim.x + threadIdx.x;
    if (idx >= KW_ELEMS) return;
    double mean = wsd[0] / (double)KW_ELEMS;
    double var  = wsd[1] / (double)KW_ELEMS - mean * mean;
    float meanf = (float)mean;
    float sigf  = sqrtf((float)var);
    float base = w[idx] - meanf;
    float acc = 0.0f;
    #pragma unroll
    for (int m = 0; m < 5; m++) {
        float arg = base + (-1.0f + 0.5f * (float)m) * sigf;
        float s = (arg > 0.0f) ? 1.0f : ((arg < 0.0f) ? -1.0f : 0.0f);
        acc += alph[m] * s;
    }
    weff[idx] = acc;
}

// ---------------- K5: fused binarize-x + 3x3 conv, 4pos x 4cout register tile ----
__device__ __forceinline__ float xeff_one(float xv, float s0, float s1, float s2,
                                          float be0, float be1, float be2) {
    float t0 = fminf(fmaxf(xv + s0, 0.0f), 1.0f) - 0.5f;
    float t1 = fminf(fmaxf(xv + s1, 0.0f), 1.0f) - 0.5f;
    float t2 = fminf(fmaxf(xv + s2, 0.0f), 1.0f) - 0.5f;
    float g0 = (t0 > 0.0f) ? 1.0f : ((t0 < 0.0f) ? -1.0f : 0.0f);
    float g1 = (t1 > 0.0f) ? 1.0f : ((t1 < 0.0f) ? -1.0f : 0.0f);
    float g2 = (t2 > 0.0f) ? 1.0f : ((t2 < 0.0f) ? -1.0f : 0.0f);
    return be0 * g0 + be1 * g1 + be2 * g2;
}

// block = (b, h, cout-half); 256 threads: tid&31 -> cout-group (4 couts),
// tid>>5 -> pos-group (4 w positions). Each thread: acc[4 pos][4 cout].
__global__ __launch_bounds__(256) void k_conv(
    const float* __restrict__ x, const float* __restrict__ shiftp,
    const float* __restrict__ beta, const void* __restrict__ wsv,
    float* __restrict__ out) {
    const float* weff = (const float*)((const char*)wsv + WS_WEFF_OFF);
    __shared__ float lds[3 * 34 * 128];   // rows h-1..h+1, positions -1..32, 128 cin

    int bid  = blockIdx.x;
    int half = bid & 1;
    int h    = (bid >> 1) & 31;
    int b    = bid >> 6;
    int tid  = threadIdx.x;

    float s0 = shiftp[0], s1 = shiftp[1], s2 = shiftp[2];
    float be0 = beta[0], be1 = beta[1], be2 = beta[2];

    // stage X_eff rows into LDS (zero pad), float4-vectorized
    for (int i = tid; i < 3 * 34 * 32; i += 256) {
        int c4  = i & 31;           // float4 group within cin
        int pos = (i >> 5) % 34;
        int dh  = (i >> 5) / 34;
        int r  = h - 1 + dh;
        int wp = pos - 1;
        float4 v = make_float4(0.0f, 0.0f, 0.0f, 0.0f);
        if (r >= 0 && r < 32 && wp >= 0 && wp < 32) {
            float4 xv = *(const float4*)(&x[(((b * 32 + r) * 32) + wp) * 128 + c4 * 4]);
            v.x = xeff_one(xv.x, s0, s1, s2, be0, be1, be2);
            v.y = xeff_one(xv.y, s0, s1, s2, be0, be1, be2);
            v.z = xeff_one(xv.z, s0, s1, s2, be0, be1, be2);
            v.w = xeff_one(xv.w, s0, s1, s2, be0, be1, be2);
        }
        *(float4*)(&lds[(dh * 34 + pos) * 128 + c4 * 4]) = v;
    }
    __syncthreads();

    int cg = tid & 31;          // cout group
    int pg = tid >> 5;          // pos group
    int c  = (half << 7) + cg * 4;
    int p0 = pg * 4;

    float acc[4][4];
    #pragma unroll
    for (int p = 0; p < 4; p++)
        #pragma unroll
        for (int j = 0; j < 4; j++) acc[p][j] = 0.0f;

    for (int dh = 0; dh < 3; dh++) {
        for (int dw = 0; dw < 3; dw++) {
            const float* wp4  = weff + (dh * 3 + dw) * (128 * 256) + c;
            const float* xrow = lds + (dh * 34 + p0 + dw) * 128;
            #pragma unroll 2
            for (int k4 = 0; k4 < 32; k4++) {
                float4 w0 = *(const float4*)(wp4 + (k4 * 4 + 0) * 256);
                float4 w1 = *(const float4*)(wp4 + (k4 * 4 + 1) * 256);
                float4 w2 = *(const float4*)(wp4 + (k4 * 4 + 2) * 256);
                float4 w3 = *(const float4*)(wp4 + (k4 * 4 + 3) * 256);
                #pragma unroll
                for (int p = 0; p < 4; p++) {
                    float4 xv = *(const float4*)(&xrow[p * 128 + k4 * 4]);
                    acc[p][0] = fmaf(xv.x, w0.x, acc[p][0]);
                    acc[p][1] = fmaf(xv.x, w0.y, acc[p][1]);
                    acc[p][2] = fmaf(xv.x, w0.z, acc[p][2]);
                    acc[p][3] = fmaf(xv.x, w0.w, acc[p][3]);
                    acc[p][0] = fmaf(xv.y, w1.x, acc[p][0]);
                    acc[p][1] = fmaf(xv.y, w1.y, acc[p][1]);
                    acc[p][2] = fmaf(xv.y, w1.z, acc[p][2]);
                    acc[p][3] = fmaf(xv.y, w1.w, acc[p][3]);
                    acc[p][0] = fmaf(xv.z, w2.x, acc[p][0]);
                    acc[p][1] = fmaf(xv.z, w2.y, acc[p][1]);
                    acc[p][2] = fmaf(xv.z, w2.z, acc[p][2]);
                    acc[p][3] = fmaf(xv.z, w2.w, acc[p][3]);
                    acc[p][0] = fmaf(xv.w, w3.x, acc[p][0]);
                    acc[p][1] = fmaf(xv.w, w3.y, acc[p][1]);
                    acc[p][2] = fmaf(xv.w, w3.z, acc[p][2]);
                    acc[p][3] = fmaf(xv.w, w3.w, acc[p][3]);
                }
            }
        }
    }

    #pragma unroll
    for (int p = 0; p < 4; p++) {
        int obase = ((b * 32 + h) * 32 + (p0 + p)) * 256 + c;
        *(float4*)(&out[obase]) = make_float4(acc[p][0], acc[p][1], acc[p][2], acc[p][3]);
    }
}

extern "C" void kernel_launch(void* const* d_in, const int* in_sizes, int n_in,
                              void* d_out, int out_size, void* d_ws, size_t ws_size,
                              hipStream_t stream) {
    const float* x      = (const float*)d_in[0];
    const float* w      = (const float*)d_in[1];
    const float* shiftp = (const float*)d_in[2];
    const float* beta   = (const float*)d_in[3];
    const float* a0     = (const float*)d_in[4];
    float* out = (float*)d_out;

    hipMemsetAsync(d_ws, 0, 160, stream);
    k_stats<<<64, 256, 0, stream>>>(w, (double*)d_ws);
    k_gc<<<64, 256, 0, stream>>>(w, d_ws);
    k_alpha<<<1, 64, 0, stream>>>(a0, d_ws);
    k_weff<<<(KW_ELEMS + 255) / 256, 256, 0, stream>>>(w, d_ws);
    k_conv<<<512, 256, 0, stream>>>(x, shiftp, beta, d_ws, out);
}